// Round 4
// baseline (19674.794 us; speedup 1.0000x reference)
//
#include <hip/hip_runtime.h>
#include <cstdint>
#include <cstddef>

typedef unsigned long long ull;

#define N_PTS  32768
#define NP1    2048
#define NSAMP1 32
#define NP2    512
#define NSAMP2 64

// ---------------- prep: xyz = points - [x,y,0], SoA ----------------
__global__ __launch_bounds__(256) void k_prep(const float* __restrict__ pts,
                                              const float* __restrict__ prop,
                                              float* __restrict__ xx,
                                              float* __restrict__ xy,
                                              float* __restrict__ xz) {
  int t = blockIdx.x * 256 + threadIdx.x;
  if (t >= N_PTS) return;
  float x = prop[0], y = prop[1];
  xx[t] = __fsub_rn(pts[3 * t + 0], x);
  xy[t] = __fsub_rn(pts[3 * t + 1], y);
  xz[t] = pts[3 * t + 2];
}

// ---------------- FPS1: 2048 of 32768, single block, 1024 threads ----------------
// 32 pts/thread. x,y,d in registers (96 VGPR + temps < 128 at 4 waves/SIMD ->
// no AGPR moves, no spill). z in 128 KB DYNAMIC LDS, point-major (2-way bank
// aliasing = free). Winner writes next centroid coords to LDS during rescan
// (static reg indexing) -> no global latency on the critical path.
#define F1T 1024
#define F1P 32

__global__ __launch_bounds__(F1T, 4) void k_fps1(const float* __restrict__ xx,
                                                 const float* __restrict__ xy,
                                                 const float* __restrict__ xz,
                                                 float* __restrict__ ox,
                                                 float* __restrict__ oy,
                                                 float* __restrict__ oz) {
  extern __shared__ float zs[];              // N_PTS floats = 128 KB
  __shared__ float wmax[F1T / 64];
  __shared__ float cc[2][3];                 // double-buffered centroid coords
  __shared__ int S[2];                       // double-buffered winner index
  int tid = threadIdx.x, lane = tid & 63, wv = tid >> 6;
  float px[F1P], py[F1P], d[F1P];
#pragma unroll
  for (int s = 0; s < F1P; ++s) {
    int i = s * F1T + tid;                   // point-major: coalesced global, free LDS
    px[s] = xx[i];
    py[s] = xy[i];
    zs[i] = xz[i];
    d[s] = 1e10f;
  }
  if (tid == 0) {
    S[0] = 0x7fffffff; S[1] = 0x7fffffff;
    cc[0][0] = xx[0]; cc[0][1] = xy[0]; cc[0][2] = xz[0];   // first centroid = point 0
  }
  __syncthreads();
  for (int it = 0; it < NP1; ++it) {
    float cx = cc[it & 1][0], cy = cc[it & 1][1], cz = cc[it & 1][2];
    if (tid == 0) { ox[it] = cx; oy[it] = cy; oz[it] = cz; }
    float bestv = -1.0f;
#pragma unroll
    for (int s = 0; s < F1P; ++s) {
      float z = zs[s * F1T + tid];
      // exact reference arithmetic: no fma, (dx^2 + dy^2) + dz^2
      float dx = __fsub_rn(px[s], cx);
      float dy = __fsub_rn(py[s], cy);
      float dz = __fsub_rn(z, cz);
      float d2 = __fadd_rn(__fadd_rn(__fmul_rn(dx, dx), __fmul_rn(dy, dy)), __fmul_rn(dz, dz));
      float dn = fminf(d[s], d2);
      d[s] = dn;
      bestv = fmaxf(bestv, dn);
    }
    float wm = bestv;
#pragma unroll
    for (int m = 1; m < 64; m <<= 1) wm = fmaxf(wm, __shfl_xor(wm, m, 64));
    if (lane == 0) wmax[wv] = wm;
    __syncthreads();                         // (A) wmax ready; cc/S reads done
    float gb = wmax[0];
#pragma unroll
    for (int k = 1; k < F1T / 64; ++k) gb = fmaxf(gb, wmax[k]);
    int n = (it + 1) & 1;
    int cand = 0x7fffffff;
    float ccx = 0.f, ccy = 0.f, ccz = 0.f;
    if (bestv == gb) {                       // only waves holding a global max pay this
#pragma unroll
      for (int s = 0; s < F1P; ++s) {
        bool m = (d[s] == gb) && (cand == 0x7fffffff);   // first (smallest) local idx
        cand = m ? (s * F1T + tid) : cand;
        ccx = m ? px[s] : ccx;
        ccy = m ? py[s] : ccy;
        ccz = m ? zs[s * F1T + tid] : ccz;
      }
      atomicMin(&S[n], cand);                // smallest point index among bit-equal maxima
    }
    __syncthreads();                         // (B) winner final
    if (cand != 0x7fffffff && cand == S[n]) {
      cc[n][0] = ccx; cc[n][1] = ccy; cc[n][2] = ccz;
    }
    if (tid == 0) S[it & 1] = 0x7fffffff;    // reset: becomes atomicMin dst at it+1
    __syncthreads();                         // (C) cc/S ready for next iter
  }
}

// ---------------- FPS2: 512 of 2048, single block, 512 threads x 4 pts ----------------
#define F2T 512
#define F2P 4
__global__ __launch_bounds__(F2T, 2) void k_fps2(const float* __restrict__ x1x,
                                                 const float* __restrict__ x1y,
                                                 const float* __restrict__ x1z,
                                                 float* __restrict__ ox,
                                                 float* __restrict__ oy,
                                                 float* __restrict__ oz) {
  __shared__ float sx[NP1], sy[NP1], sz[NP1];
  __shared__ float wmax[F2T / 64];
  __shared__ int S[2];
  int tid = threadIdx.x;
  float px[F2P], py[F2P], pz[F2P], d[F2P];
#pragma unroll
  for (int s = 0; s < F2P; ++s) {
    int i = s * F2T + tid;
    px[s] = x1x[i]; py[s] = x1y[i]; pz[s] = x1z[i];
    sx[i] = px[s];  sy[i] = py[s];  sz[i] = pz[s];
    d[s] = 1e10f;
  }
  if (tid == 0) { S[0] = 0; S[1] = 0x7fffffff; }
  __syncthreads();
  for (int it = 0; it < NP2; ++it) {
    int f = __builtin_amdgcn_readfirstlane(S[it & 1]);
    float cx = sx[f], cy = sy[f], cz = sz[f];
    if (tid == 0) { ox[it] = cx; oy[it] = cy; oz[it] = cz; }
    float bestv = -1.0f;
#pragma unroll
    for (int s = 0; s < F2P; ++s) {
      float dx = __fsub_rn(px[s], cx);
      float dy = __fsub_rn(py[s], cy);
      float dz = __fsub_rn(pz[s], cz);
      float d2 = __fadd_rn(__fadd_rn(__fmul_rn(dx, dx), __fmul_rn(dy, dy)), __fmul_rn(dz, dz));
      float dn = fminf(d[s], d2);
      d[s] = dn;
      bestv = fmaxf(bestv, dn);
    }
    float wv = bestv;
#pragma unroll
    for (int m = 1; m < 64; m <<= 1) wv = fmaxf(wv, __shfl_xor(wv, m, 64));
    if ((tid & 63) == 0) wmax[tid >> 6] = wv;
    __syncthreads();
    float gb = wmax[0];
#pragma unroll
    for (int k = 1; k < F2T / 64; ++k) gb = fmaxf(gb, wmax[k]);
    if (bestv == gb) {
      int cand = 0x7fffffff;
#pragma unroll
      for (int s = F2P - 1; s >= 0; --s) cand = (d[s] == gb) ? (s * F2T + tid) : cand;
      atomicMin(&S[(it + 1) & 1], cand);
    }
    if (tid == 0) S[it & 1] = 0x7fffffff;
    __syncthreads();
  }
}

// ---------------- ball query ----------------
__global__ void k_ballq(const float* __restrict__ px, const float* __restrict__ py,
                        const float* __restrict__ pz, int n,
                        const float* __restrict__ qx, const float* __restrict__ qy,
                        const float* __restrict__ qz, int S,
                        float r2, int ns, int* __restrict__ out) {
  int w = (blockIdx.x * (int)blockDim.x + threadIdx.x) >> 6;
  int lane = threadIdx.x & 63;
  if (w >= S) return;
  float cx = qx[w], cy = qy[w], cz = qz[w];
  int found = 0, first = 0;
  bool havefirst = false;
  for (int base = 0; base < n && found < ns; base += 64) {
    int i = base + lane;
    float dx = __fsub_rn(px[i], cx);
    float dy = __fsub_rn(py[i], cy);
    float dz = __fsub_rn(pz[i], cz);
    float d2 = __fadd_rn(__fadd_rn(__fmul_rn(dx, dx), __fmul_rn(dy, dy)), __fmul_rn(dz, dz));
    bool isin = d2 <= r2;
    ull m = __ballot(isin);
    if (!havefirst && m != 0ull) { first = base + __builtin_ctzll(m); havefirst = true; }
    if (isin) {
      int r = (int)__popcll(m & ((1ull << lane) - 1ull));
      int slot = found + r;
      if (slot < ns) out[w * ns + slot] = i;
    }
    found += (int)__popcll(m);
  }
  for (int s2 = found + lane; s2 < ns; s2 += 64) out[w * ns + s2] = first;
}

// ---------------- gather SA1 input rows (15 ch) ----------------
__global__ __launch_bounds__(256) void k_gather1(const float* __restrict__ pts,
                                                 const float* __restrict__ prop,
                                                 const float* __restrict__ xx,
                                                 const float* __restrict__ xy,
                                                 const float* __restrict__ xz,
                                                 const float* __restrict__ x1x,
                                                 const float* __restrict__ x1y,
                                                 const float* __restrict__ x1z,
                                                 const int* __restrict__ gidx,
                                                 float* __restrict__ X, int rbase) {
  int rl = blockIdx.x * 256 + threadIdx.x;
  if (rl >= 8192) return;
  int r = rbase + rl;
  int s = r >> 5;
  int g = gidx[r];
  float x = prop[0], y = prop[1], wz = prop[3];
  float w2 = wz * 0.5f;
  float oxp = __fadd_rn(x, w2), oxm = __fsub_rn(x, w2);
  float oyp = __fadd_rn(y, w2), oym = __fsub_rn(y, w2);
  float gx = xx[g], gy = xy[g], gz = xz[g];
  float pxv = pts[3 * g + 0], pyv = pts[3 * g + 1];
  float* o = X + (size_t)rl * 15;
  o[0] = __fsub_rn(gx, x1x[s]);
  o[1] = __fsub_rn(gy, x1y[s]);
  o[2] = __fsub_rn(gz, x1z[s]);
  o[3] = __fsub_rn(pxv, oxp);  o[4]  = gy;                    o[5]  = gz;
  o[6] = __fsub_rn(pxv, oxm);  o[7]  = gy;                    o[8]  = gz;
  o[9] = gx;                   o[10] = __fsub_rn(pyv, oyp);   o[11] = gz;
  o[12] = gx;                  o[13] = __fsub_rn(pyv, oym);   o[14] = gz;
}

// ---------------- gather SA2 input rows (131 ch) ----------------
__global__ __launch_bounds__(256) void k_gather2(const float* __restrict__ x1x,
                                                 const float* __restrict__ x1y,
                                                 const float* __restrict__ x1z,
                                                 const float* __restrict__ x2x,
                                                 const float* __restrict__ x2y,
                                                 const float* __restrict__ x2z,
                                                 const int* __restrict__ gidx,
                                                 const float* __restrict__ f1,
                                                 float* __restrict__ X, int rbase) {
  int e = blockIdx.x * 256 + threadIdx.x;
  if (e >= 8192 * 131) return;
  int rl = e / 131, c = e % 131;
  int r = rbase + rl;
  int s = r >> 6;
  int g = gidx[r];
  float v;
  if (c == 0)      v = __fsub_rn(x1x[g], x2x[s]);
  else if (c == 1) v = __fsub_rn(x1y[g], x2y[s]);
  else if (c == 2) v = __fsub_rn(x1z[g], x2z[s]);
  else             v = f1[(size_t)g * 128 + (c - 3)];
  X[e] = v;
}

// ---------------- gather SA3 input rows (259 ch) ----------------
__global__ __launch_bounds__(256) void k_gather3(const float* __restrict__ x2x,
                                                 const float* __restrict__ x2y,
                                                 const float* __restrict__ x2z,
                                                 const float* __restrict__ f2,
                                                 float* __restrict__ X) {
  int e = blockIdx.x * 256 + threadIdx.x;
  if (e >= 512 * 259) return;
  int rl = e / 259, c = e % 259;
  float v;
  if (c == 0)      v = x2x[rl];
  else if (c == 1) v = x2y[rl];
  else if (c == 2) v = x2z[rl];
  else             v = f2[(size_t)rl * 256 + (c - 3)];
  X[e] = v;
}

// ---------------- relu GEMM ----------------
__global__ __launch_bounds__(256) void k_gemm(const float* __restrict__ A,
                                              const float* __restrict__ W,
                                              const float* __restrict__ bias,
                                              float* __restrict__ C,
                                              int M, int N, int K) {
  __shared__ __align__(16) float As[16][68];
  __shared__ __align__(16) float Bs[16][68];
  int tid = threadIdx.x;
  int bn = blockIdx.x * 64, bm = blockIdx.y * 64;
  int tx = tid & 15, ty = tid >> 4;
  float acc[4][4] = {{0.f, 0.f, 0.f, 0.f}, {0.f, 0.f, 0.f, 0.f},
                     {0.f, 0.f, 0.f, 0.f}, {0.f, 0.f, 0.f, 0.f}};
  for (int k0 = 0; k0 < K; k0 += 16) {
#pragma unroll
    for (int e = 0; e < 4; ++e) {
      int flat = tid + e * 256;
      int rr = flat >> 4, cc = flat & 15;
      As[cc][rr] = (k0 + cc < K) ? A[(size_t)(bm + rr) * K + (k0 + cc)] : 0.0f;
      Bs[cc][rr] = (k0 + cc < K) ? W[(size_t)(bn + rr) * K + (k0 + cc)] : 0.0f;
    }
    __syncthreads();
#pragma unroll
    for (int kk = 0; kk < 16; ++kk) {
      const float4 a = *(const float4*)&As[kk][ty * 4];
      const float4 b = *(const float4*)&Bs[kk][tx * 4];
      float av[4] = {a.x, a.y, a.z, a.w};
      float bb[4] = {b.x, b.y, b.z, b.w};
#pragma unroll
      for (int i = 0; i < 4; ++i)
#pragma unroll
        for (int j = 0; j < 4; ++j)
          acc[i][j] = fmaf(av[i], bb[j], acc[i][j]);
    }
    __syncthreads();
  }
#pragma unroll
  for (int i = 0; i < 4; ++i) {
    int m = bm + ty * 4 + i;
    float4 o;
    o.x = fmaxf(acc[i][0] + bias[bn + tx * 4 + 0], 0.0f);
    o.y = fmaxf(acc[i][1] + bias[bn + tx * 4 + 1], 0.0f);
    o.z = fmaxf(acc[i][2] + bias[bn + tx * 4 + 2], 0.0f);
    o.w = fmaxf(acc[i][3] + bias[bn + tx * 4 + 3], 0.0f);
    *(float4*)&C[(size_t)m * N + bn + tx * 4] = o;
  }
}

// ---------------- maxpool ----------------
__global__ __launch_bounds__(256) void k_maxpool(const float* __restrict__ H,
                                                 float* __restrict__ F,
                                                 int S, int Ks, int Nch, int sbase) {
  int t = blockIdx.x * 256 + threadIdx.x;
  if (t >= S * Nch) return;
  int sl = t / Nch, n = t % Nch;
  const float* p = H + (size_t)sl * Ks * Nch + n;
  float m = p[0];
  for (int k = 1; k < Ks; ++k) m = fmaxf(m, p[(size_t)k * Nch]);
  F[(size_t)(sbase + sl) * Nch + n] = m;
}

// ---------------- host ----------------
extern "C" void kernel_launch(void* const* d_in, const int* in_sizes, int n_in,
                              void* d_out, int out_size, void* d_ws, size_t ws_size,
                              hipStream_t stream) {
  (void)n_in; (void)out_size; (void)ws_size;
  const float* pts = (const float*)d_in[0];
  const float* prop = (const float*)d_in[1];

  bool dict_order = (in_sizes[3] == 64);
  const float *w[3][3], *b[3][3];
  for (int g = 0; g < 3; ++g)
    for (int l = 0; l < 3; ++l) {
      int base = 2 + g * 6;
      int wi = dict_order ? (base + l * 2) : (base + l);
      int bi = dict_order ? (base + l * 2 + 1) : (base + 3 + l);
      w[g][l] = (const float*)d_in[wi];
      b[g][l] = (const float*)d_in[bi];
    }

  float* ws = (float*)d_ws;
  float* xx = ws;
  float* xy = xx + N_PTS;
  float* xz = xy + N_PTS;
  float* x1x = xz + N_PTS;
  float* x1y = x1x + NP1;
  float* x1z = x1y + NP1;
  float* x2x = x1z + NP1;
  float* x2y = x2x + NP2;
  float* x2z = x2y + NP2;
  int* gidx1 = (int*)(x2z + NP2);
  int* gidx2 = gidx1 + NP1 * NSAMP1;
  float* f1 = (float*)(gidx2 + NP2 * NSAMP2);
  float* f2 = f1 + NP1 * 128;
  float* Xp = f2 + NP2 * 256;
  float* Ha = Xp + 8192 * 131;
  float* Hb = Ha + 8192 * 128;
  float* Hc = Hb + 8192 * 128;

  const float R2A = (float)(0.4 * 0.4);
  const float R2B = (float)(0.8 * 0.8);
  const int F1LDS = N_PTS * (int)sizeof(float);   // 128 KB dynamic LDS

  // allow >64 KB dynamic LDS for k_fps1 (not a stream op; graph-capture safe)
  hipFuncSetAttribute((const void*)k_fps1,
                      hipFuncAttributeMaxDynamicSharedMemorySize, F1LDS);

  k_prep<<<128, 256, 0, stream>>>(pts, prop, xx, xy, xz);
  k_fps1<<<1, F1T, F1LDS, stream>>>(xx, xy, xz, x1x, x1y, x1z);
  k_fps2<<<1, F2T, 0, stream>>>(x1x, x1y, x1z, x2x, x2y, x2z);
  k_ballq<<<512, 256, 0, stream>>>(xx, xy, xz, N_PTS, x1x, x1y, x1z, NP1, R2A, NSAMP1, gidx1);
  k_ballq<<<128, 256, 0, stream>>>(x1x, x1y, x1z, NP1, x2x, x2y, x2z, NP2, R2B, NSAMP2, gidx2);

  for (int ch = 0; ch < 8; ++ch) {
    int rbase = ch * 8192;
    k_gather1<<<32, 256, 0, stream>>>(pts, prop, xx, xy, xz, x1x, x1y, x1z, gidx1, Xp, rbase);
    k_gemm<<<dim3(1, 128), 256, 0, stream>>>(Xp, w[0][0], b[0][0], Ha, 8192, 64, 15);
    k_gemm<<<dim3(1, 128), 256, 0, stream>>>(Ha, w[0][1], b[0][1], Hb, 8192, 64, 64);
    k_gemm<<<dim3(2, 128), 256, 0, stream>>>(Hb, w[0][2], b[0][2], Hc, 8192, 128, 64);
    k_maxpool<<<128, 256, 0, stream>>>(Hc, f1, 256, 32, 128, ch * 256);
  }

  for (int ch = 0; ch < 4; ++ch) {
    int rbase = ch * 8192;
    k_gather2<<<(8192 * 131 + 255) / 256, 256, 0, stream>>>(x1x, x1y, x1z, x2x, x2y, x2z,
                                                            gidx2, f1, Xp, rbase);
    k_gemm<<<dim3(2, 128), 256, 0, stream>>>(Xp, w[1][0], b[1][0], Ha, 8192, 128, 131);
    k_gemm<<<dim3(2, 128), 256, 0, stream>>>(Ha, w[1][1], b[1][1], Hb, 8192, 128, 128);
    k_gemm<<<dim3(4, 128), 256, 0, stream>>>(Hb, w[1][2], b[1][2], Hc, 8192, 256, 128);
    k_maxpool<<<128, 256, 0, stream>>>(Hc, f2, 128, 64, 256, ch * 128);
  }

  k_gather3<<<(512 * 259 + 255) / 256, 256, 0, stream>>>(x2x, x2y, x2z, f2, Xp);
  k_gemm<<<dim3(4, 8), 256, 0, stream>>>(Xp, w[2][0], b[2][0], Ha, 512, 256, 259);
  k_gemm<<<dim3(8, 8), 256, 0, stream>>>(Ha, w[2][1], b[2][1], Hb, 512, 512, 256);
  k_gemm<<<dim3(16, 8), 256, 0, stream>>>(Hb, w[2][2], b[2][2], Hc, 512, 1024, 512);
  k_maxpool<<<4, 256, 0, stream>>>(Hc, (float*)d_out, 1, 512, 1024, 0);
}

// Round 5
// 19662.512 us; speedup vs baseline: 1.0006x; 1.0006x over previous
//
#include <hip/hip_runtime.h>
#include <cstdint>
#include <cstddef>

typedef unsigned long long ull;

#define N_PTS  32768
#define NP1    2048
#define NSAMP1 32
#define NP2    512
#define NSAMP2 64

// ---------------- prep: xyz = points - [x,y,0], SoA ----------------
__global__ __launch_bounds__(256) void k_prep(const float* __restrict__ pts,
                                              const float* __restrict__ prop,
                                              float* __restrict__ xx,
                                              float* __restrict__ xy,
                                              float* __restrict__ xz) {
  int t = blockIdx.x * 256 + threadIdx.x;
  if (t >= N_PTS) return;
  float x = prop[0], y = prop[1];
  xx[t] = __fsub_rn(pts[3 * t + 0], x);
  xy[t] = __fsub_rn(pts[3 * t + 1], y);
  xz[t] = pts[3 * t + 2];
}

// ---------------- FPS1: 2048 of 32768, single block, 1024 threads ----------------
// 32 pts/thread. x,y,d in registers (96 + ~20 temps). z in 128 KB DYNAMIC LDS,
// point-major (2-way bank aliasing = free).
// REGISTER CONTRACT (measured r2/r4): hipcc arch-VGPR cap = 256/min_waves_per_EU.
//   (512,2)->128, (1024,4)->64 (scratch spill, 18.7ms). So declare (1024,2):
//   cap 128 arch VGPRs; 4 waves/SIMD x 128 = 512 = full file, still resident.
#define F1T 1024
#define F1P 32

__global__ __launch_bounds__(F1T, 2) void k_fps1(const float* __restrict__ xx,
                                                 const float* __restrict__ xy,
                                                 const float* __restrict__ xz,
                                                 float* __restrict__ ox,
                                                 float* __restrict__ oy,
                                                 float* __restrict__ oz) {
  extern __shared__ float zs[];              // N_PTS floats = 128 KB
  __shared__ float wmax[F1T / 64];
  __shared__ float cc[2][3];                 // double-buffered centroid coords
  __shared__ int S[2];                       // double-buffered winner index
  int tid = threadIdx.x, lane = tid & 63, wv = tid >> 6;
  float px[F1P], py[F1P], d[F1P];
#pragma unroll
  for (int s = 0; s < F1P; ++s) {
    int i = s * F1T + tid;                   // point-major: coalesced global, free LDS
    px[s] = xx[i];
    py[s] = xy[i];
    zs[i] = xz[i];
    d[s] = 1e10f;
  }
  if (tid == 0) {
    S[0] = 0x7fffffff; S[1] = 0x7fffffff;
    cc[0][0] = xx[0]; cc[0][1] = xy[0]; cc[0][2] = xz[0];   // first centroid = point 0
  }
  __syncthreads();
  for (int it = 0; it < NP1; ++it) {
    float cx = cc[it & 1][0], cy = cc[it & 1][1], cz = cc[it & 1][2];
    if (tid == 0) { ox[it] = cx; oy[it] = cy; oz[it] = cz; }
    float bestv = -1.0f;
#pragma unroll
    for (int s = 0; s < F1P; ++s) {
      float z = zs[s * F1T + tid];
      // exact reference arithmetic: no fma, (dx^2 + dy^2) + dz^2
      float dx = __fsub_rn(px[s], cx);
      float dy = __fsub_rn(py[s], cy);
      float dz = __fsub_rn(z, cz);
      float d2 = __fadd_rn(__fadd_rn(__fmul_rn(dx, dx), __fmul_rn(dy, dy)), __fmul_rn(dz, dz));
      float dn = fminf(d[s], d2);
      d[s] = dn;
      bestv = fmaxf(bestv, dn);
    }
    float wm = bestv;
#pragma unroll
    for (int m = 1; m < 64; m <<= 1) wm = fmaxf(wm, __shfl_xor(wm, m, 64));
    if (lane == 0) wmax[wv] = wm;
    __syncthreads();                         // (A) wmax ready; cc/S reads done
    float gb = wmax[0];
#pragma unroll
    for (int k = 1; k < F1T / 64; ++k) gb = fmaxf(gb, wmax[k]);
    int n = (it + 1) & 1;
    int cand = 0x7fffffff;
    float ccx = 0.f, ccy = 0.f, ccz = 0.f;
    if (bestv == gb) {                       // only waves holding a global max pay this
#pragma unroll
      for (int s = 0; s < F1P; ++s) {
        bool m = (d[s] == gb) && (cand == 0x7fffffff);   // first (smallest) local idx
        cand = m ? (s * F1T + tid) : cand;
        ccx = m ? px[s] : ccx;
        ccy = m ? py[s] : ccy;
        ccz = m ? zs[s * F1T + tid] : ccz;
      }
      atomicMin(&S[n], cand);                // smallest point index among bit-equal maxima
    }
    __syncthreads();                         // (B) winner final
    if (cand != 0x7fffffff && cand == S[n]) {
      cc[n][0] = ccx; cc[n][1] = ccy; cc[n][2] = ccz;
    }
    if (tid == 0) S[it & 1] = 0x7fffffff;    // reset: becomes atomicMin dst at it+1
    __syncthreads();                         // (C) cc/S ready for next iter
  }
}

// ---------------- FPS2: 512 of 2048, single block, 512 threads x 4 pts ----------------
#define F2T 512
#define F2P 4
__global__ __launch_bounds__(F2T, 2) void k_fps2(const float* __restrict__ x1x,
                                                 const float* __restrict__ x1y,
                                                 const float* __restrict__ x1z,
                                                 float* __restrict__ ox,
                                                 float* __restrict__ oy,
                                                 float* __restrict__ oz) {
  __shared__ float sx[NP1], sy[NP1], sz[NP1];
  __shared__ float wmax[F2T / 64];
  __shared__ int S[2];
  int tid = threadIdx.x;
  float px[F2P], py[F2P], pz[F2P], d[F2P];
#pragma unroll
  for (int s = 0; s < F2P; ++s) {
    int i = s * F2T + tid;
    px[s] = x1x[i]; py[s] = x1y[i]; pz[s] = x1z[i];
    sx[i] = px[s];  sy[i] = py[s];  sz[i] = pz[s];
    d[s] = 1e10f;
  }
  if (tid == 0) { S[0] = 0; S[1] = 0x7fffffff; }
  __syncthreads();
  for (int it = 0; it < NP2; ++it) {
    int f = __builtin_amdgcn_readfirstlane(S[it & 1]);
    float cx = sx[f], cy = sy[f], cz = sz[f];
    if (tid == 0) { ox[it] = cx; oy[it] = cy; oz[it] = cz; }
    float bestv = -1.0f;
#pragma unroll
    for (int s = 0; s < F2P; ++s) {
      float dx = __fsub_rn(px[s], cx);
      float dy = __fsub_rn(py[s], cy);
      float dz = __fsub_rn(pz[s], cz);
      float d2 = __fadd_rn(__fadd_rn(__fmul_rn(dx, dx), __fmul_rn(dy, dy)), __fmul_rn(dz, dz));
      float dn = fminf(d[s], d2);
      d[s] = dn;
      bestv = fmaxf(bestv, dn);
    }
    float wv = bestv;
#pragma unroll
    for (int m = 1; m < 64; m <<= 1) wv = fmaxf(wv, __shfl_xor(wv, m, 64));
    if ((tid & 63) == 0) wmax[tid >> 6] = wv;
    __syncthreads();
    float gb = wmax[0];
#pragma unroll
    for (int k = 1; k < F2T / 64; ++k) gb = fmaxf(gb, wmax[k]);
    if (bestv == gb) {
      int cand = 0x7fffffff;
#pragma unroll
      for (int s = F2P - 1; s >= 0; --s) cand = (d[s] == gb) ? (s * F2T + tid) : cand;
      atomicMin(&S[(it + 1) & 1], cand);
    }
    if (tid == 0) S[it & 1] = 0x7fffffff;
    __syncthreads();
  }
}

// ---------------- ball query ----------------
__global__ void k_ballq(const float* __restrict__ px, const float* __restrict__ py,
                        const float* __restrict__ pz, int n,
                        const float* __restrict__ qx, const float* __restrict__ qy,
                        const float* __restrict__ qz, int S,
                        float r2, int ns, int* __restrict__ out) {
  int w = (blockIdx.x * (int)blockDim.x + threadIdx.x) >> 6;
  int lane = threadIdx.x & 63;
  if (w >= S) return;
  float cx = qx[w], cy = qy[w], cz = qz[w];
  int found = 0, first = 0;
  bool havefirst = false;
  for (int base = 0; base < n && found < ns; base += 64) {
    int i = base + lane;
    float dx = __fsub_rn(px[i], cx);
    float dy = __fsub_rn(py[i], cy);
    float dz = __fsub_rn(pz[i], cz);
    float d2 = __fadd_rn(__fadd_rn(__fmul_rn(dx, dx), __fmul_rn(dy, dy)), __fmul_rn(dz, dz));
    bool isin = d2 <= r2;
    ull m = __ballot(isin);
    if (!havefirst && m != 0ull) { first = base + __builtin_ctzll(m); havefirst = true; }
    if (isin) {
      int r = (int)__popcll(m & ((1ull << lane) - 1ull));
      int slot = found + r;
      if (slot < ns) out[w * ns + slot] = i;
    }
    found += (int)__popcll(m);
  }
  for (int s2 = found + lane; s2 < ns; s2 += 64) out[w * ns + s2] = first;
}

// ---------------- gather SA1 input rows (15 ch) ----------------
__global__ __launch_bounds__(256) void k_gather1(const float* __restrict__ pts,
                                                 const float* __restrict__ prop,
                                                 const float* __restrict__ xx,
                                                 const float* __restrict__ xy,
                                                 const float* __restrict__ xz,
                                                 const float* __restrict__ x1x,
                                                 const float* __restrict__ x1y,
                                                 const float* __restrict__ x1z,
                                                 const int* __restrict__ gidx,
                                                 float* __restrict__ X, int rbase) {
  int rl = blockIdx.x * 256 + threadIdx.x;
  if (rl >= 8192) return;
  int r = rbase + rl;
  int s = r >> 5;
  int g = gidx[r];
  float x = prop[0], y = prop[1], wz = prop[3];
  float w2 = wz * 0.5f;
  float oxp = __fadd_rn(x, w2), oxm = __fsub_rn(x, w2);
  float oyp = __fadd_rn(y, w2), oym = __fsub_rn(y, w2);
  float gx = xx[g], gy = xy[g], gz = xz[g];
  float pxv = pts[3 * g + 0], pyv = pts[3 * g + 1];
  float* o = X + (size_t)rl * 15;
  o[0] = __fsub_rn(gx, x1x[s]);
  o[1] = __fsub_rn(gy, x1y[s]);
  o[2] = __fsub_rn(gz, x1z[s]);
  o[3] = __fsub_rn(pxv, oxp);  o[4]  = gy;                    o[5]  = gz;
  o[6] = __fsub_rn(pxv, oxm);  o[7]  = gy;                    o[8]  = gz;
  o[9] = gx;                   o[10] = __fsub_rn(pyv, oyp);   o[11] = gz;
  o[12] = gx;                  o[13] = __fsub_rn(pyv, oym);   o[14] = gz;
}

// ---------------- gather SA2 input rows (131 ch) ----------------
__global__ __launch_bounds__(256) void k_gather2(const float* __restrict__ x1x,
                                                 const float* __restrict__ x1y,
                                                 const float* __restrict__ x1z,
                                                 const float* __restrict__ x2x,
                                                 const float* __restrict__ x2y,
                                                 const float* __restrict__ x2z,
                                                 const int* __restrict__ gidx,
                                                 const float* __restrict__ f1,
                                                 float* __restrict__ X, int rbase) {
  int e = blockIdx.x * 256 + threadIdx.x;
  if (e >= 8192 * 131) return;
  int rl = e / 131, c = e % 131;
  int r = rbase + rl;
  int s = r >> 6;
  int g = gidx[r];
  float v;
  if (c == 0)      v = __fsub_rn(x1x[g], x2x[s]);
  else if (c == 1) v = __fsub_rn(x1y[g], x2y[s]);
  else if (c == 2) v = __fsub_rn(x1z[g], x2z[s]);
  else             v = f1[(size_t)g * 128 + (c - 3)];
  X[e] = v;
}

// ---------------- gather SA3 input rows (259 ch) ----------------
__global__ __launch_bounds__(256) void k_gather3(const float* __restrict__ x2x,
                                                 const float* __restrict__ x2y,
                                                 const float* __restrict__ x2z,
                                                 const float* __restrict__ f2,
                                                 float* __restrict__ X) {
  int e = blockIdx.x * 256 + threadIdx.x;
  if (e >= 512 * 259) return;
  int rl = e / 259, c = e % 259;
  float v;
  if (c == 0)      v = x2x[rl];
  else if (c == 1) v = x2y[rl];
  else if (c == 2) v = x2z[rl];
  else             v = f2[(size_t)rl * 256 + (c - 3)];
  X[e] = v;
}

// ---------------- relu GEMM ----------------
__global__ __launch_bounds__(256) void k_gemm(const float* __restrict__ A,
                                              const float* __restrict__ W,
                                              const float* __restrict__ bias,
                                              float* __restrict__ C,
                                              int M, int N, int K) {
  __shared__ __align__(16) float As[16][68];
  __shared__ __align__(16) float Bs[16][68];
  int tid = threadIdx.x;
  int bn = blockIdx.x * 64, bm = blockIdx.y * 64;
  int tx = tid & 15, ty = tid >> 4;
  float acc[4][4] = {{0.f, 0.f, 0.f, 0.f}, {0.f, 0.f, 0.f, 0.f},
                     {0.f, 0.f, 0.f, 0.f}, {0.f, 0.f, 0.f, 0.f}};
  for (int k0 = 0; k0 < K; k0 += 16) {
#pragma unroll
    for (int e = 0; e < 4; ++e) {
      int flat = tid + e * 256;
      int rr = flat >> 4, cc = flat & 15;
      As[cc][rr] = (k0 + cc < K) ? A[(size_t)(bm + rr) * K + (k0 + cc)] : 0.0f;
      Bs[cc][rr] = (k0 + cc < K) ? W[(size_t)(bn + rr) * K + (k0 + cc)] : 0.0f;
    }
    __syncthreads();
#pragma unroll
    for (int kk = 0; kk < 16; ++kk) {
      const float4 a = *(const float4*)&As[kk][ty * 4];
      const float4 b = *(const float4*)&Bs[kk][tx * 4];
      float av[4] = {a.x, a.y, a.z, a.w};
      float bb[4] = {b.x, b.y, b.z, b.w};
#pragma unroll
      for (int i = 0; i < 4; ++i)
#pragma unroll
        for (int j = 0; j < 4; ++j)
          acc[i][j] = fmaf(av[i], bb[j], acc[i][j]);
    }
    __syncthreads();
  }
#pragma unroll
  for (int i = 0; i < 4; ++i) {
    int m = bm + ty * 4 + i;
    float4 o;
    o.x = fmaxf(acc[i][0] + bias[bn + tx * 4 + 0], 0.0f);
    o.y = fmaxf(acc[i][1] + bias[bn + tx * 4 + 1], 0.0f);
    o.z = fmaxf(acc[i][2] + bias[bn + tx * 4 + 2], 0.0f);
    o.w = fmaxf(acc[i][3] + bias[bn + tx * 4 + 3], 0.0f);
    *(float4*)&C[(size_t)m * N + bn + tx * 4] = o;
  }
}

// ---------------- maxpool ----------------
__global__ __launch_bounds__(256) void k_maxpool(const float* __restrict__ H,
                                                 float* __restrict__ F,
                                                 int S, int Ks, int Nch, int sbase) {
  int t = blockIdx.x * 256 + threadIdx.x;
  if (t >= S * Nch) return;
  int sl = t / Nch, n = t % Nch;
  const float* p = H + (size_t)sl * Ks * Nch + n;
  float m = p[0];
  for (int k = 1; k < Ks; ++k) m = fmaxf(m, p[(size_t)k * Nch]);
  F[(size_t)(sbase + sl) * Nch + n] = m;
}

// ---------------- host ----------------
extern "C" void kernel_launch(void* const* d_in, const int* in_sizes, int n_in,
                              void* d_out, int out_size, void* d_ws, size_t ws_size,
                              hipStream_t stream) {
  (void)n_in; (void)out_size; (void)ws_size;
  const float* pts = (const float*)d_in[0];
  const float* prop = (const float*)d_in[1];

  bool dict_order = (in_sizes[3] == 64);
  const float *w[3][3], *b[3][3];
  for (int g = 0; g < 3; ++g)
    for (int l = 0; l < 3; ++l) {
      int base = 2 + g * 6;
      int wi = dict_order ? (base + l * 2) : (base + l);
      int bi = dict_order ? (base + l * 2 + 1) : (base + 3 + l);
      w[g][l] = (const float*)d_in[wi];
      b[g][l] = (const float*)d_in[bi];
    }

  float* ws = (float*)d_ws;
  float* xx = ws;
  float* xy = xx + N_PTS;
  float* xz = xy + N_PTS;
  float* x1x = xz + N_PTS;
  float* x1y = x1x + NP1;
  float* x1z = x1y + NP1;
  float* x2x = x1z + NP1;
  float* x2y = x2x + NP2;
  float* x2z = x2y + NP2;
  int* gidx1 = (int*)(x2z + NP2);
  int* gidx2 = gidx1 + NP1 * NSAMP1;
  float* f1 = (float*)(gidx2 + NP2 * NSAMP2);
  float* f2 = f1 + NP1 * 128;
  float* Xp = f2 + NP2 * 256;
  float* Ha = Xp + 8192 * 131;
  float* Hb = Ha + 8192 * 128;
  float* Hc = Hb + 8192 * 128;

  const float R2A = (float)(0.4 * 0.4);
  const float R2B = (float)(0.8 * 0.8);
  const int F1LDS = N_PTS * (int)sizeof(float);   // 128 KB dynamic LDS

  hipFuncSetAttribute((const void*)k_fps1,
                      hipFuncAttributeMaxDynamicSharedMemorySize, F1LDS);

  k_prep<<<128, 256, 0, stream>>>(pts, prop, xx, xy, xz);
  k_fps1<<<1, F1T, F1LDS, stream>>>(xx, xy, xz, x1x, x1y, x1z);
  k_fps2<<<1, F2T, 0, stream>>>(x1x, x1y, x1z, x2x, x2y, x2z);
  k_ballq<<<512, 256, 0, stream>>>(xx, xy, xz, N_PTS, x1x, x1y, x1z, NP1, R2A, NSAMP1, gidx1);
  k_ballq<<<128, 256, 0, stream>>>(x1x, x1y, x1z, NP1, x2x, x2y, x2z, NP2, R2B, NSAMP2, gidx2);

  for (int ch = 0; ch < 8; ++ch) {
    int rbase = ch * 8192;
    k_gather1<<<32, 256, 0, stream>>>(pts, prop, xx, xy, xz, x1x, x1y, x1z, gidx1, Xp, rbase);
    k_gemm<<<dim3(1, 128), 256, 0, stream>>>(Xp, w[0][0], b[0][0], Ha, 8192, 64, 15);
    k_gemm<<<dim3(1, 128), 256, 0, stream>>>(Ha, w[0][1], b[0][1], Hb, 8192, 64, 64);
    k_gemm<<<dim3(2, 128), 256, 0, stream>>>(Hb, w[0][2], b[0][2], Hc, 8192, 128, 64);
    k_maxpool<<<128, 256, 0, stream>>>(Hc, f1, 256, 32, 128, ch * 256);
  }

  for (int ch = 0; ch < 4; ++ch) {
    int rbase = ch * 8192;
    k_gather2<<<(8192 * 131 + 255) / 256, 256, 0, stream>>>(x1x, x1y, x1z, x2x, x2y, x2z,
                                                            gidx2, f1, Xp, rbase);
    k_gemm<<<dim3(2, 128), 256, 0, stream>>>(Xp, w[1][0], b[1][0], Ha, 8192, 128, 131);
    k_gemm<<<dim3(2, 128), 256, 0, stream>>>(Ha, w[1][1], b[1][1], Hb, 8192, 128, 128);
    k_gemm<<<dim3(4, 128), 256, 0, stream>>>(Hb, w[1][2], b[1][2], Hc, 8192, 256, 128);
    k_maxpool<<<128, 256, 0, stream>>>(Hc, f2, 128, 64, 256, ch * 128);
  }

  k_gather3<<<(512 * 259 + 255) / 256, 256, 0, stream>>>(x2x, x2y, x2z, f2, Xp);
  k_gemm<<<dim3(4, 8), 256, 0, stream>>>(Xp, w[2][0], b[2][0], Ha, 512, 256, 259);
  k_gemm<<<dim3(8, 8), 256, 0, stream>>>(Ha, w[2][1], b[2][1], Hb, 512, 512, 256);
  k_gemm<<<dim3(16, 8), 256, 0, stream>>>(Hb, w[2][2], b[2][2], Hc, 512, 1024, 512);
  k_maxpool<<<4, 256, 0, stream>>>(Hc, (float*)d_out, 1, 512, 1024, 0);
}

// Round 6
// 12230.385 us; speedup vs baseline: 1.6087x; 1.6077x over previous
//
#include <hip/hip_runtime.h>
#include <cstdint>
#include <cstddef>

typedef unsigned long long ull;
typedef float v2f __attribute__((ext_vector_type(2)));

#define N_PTS  32768
#define NP1    2048
#define NSAMP1 32
#define NP2    512
#define NSAMP2 64

// ---------------- prep: xyz = points - [x,y,0], SoA ----------------
__global__ __launch_bounds__(256) void k_prep(const float* __restrict__ pts,
                                              const float* __restrict__ prop,
                                              float* __restrict__ xx,
                                              float* __restrict__ xy,
                                              float* __restrict__ xz) {
  int t = blockIdx.x * 256 + threadIdx.x;
  if (t >= N_PTS) return;
  float x = prop[0], y = prop[1];
  xx[t] = __fsub_rn(pts[3 * t + 0], x);
  xy[t] = __fsub_rn(pts[3 * t + 1], y);
  xz[t] = pts[3 * t + 2];
}

// ---------------- FPS1: 2048 of 32768, single block, 512 threads ----------------
// Point-PAIRS as float2: px/py/d = 32 v2f each (192 regs; fits 256-unified/wave
// at block 512 -> no scratch; ~84 overflow regs land in AGPR, mild move cost).
// z pairs in 128 KB dynamic LDS (ds_read_b64). v2f math legalizes to
// v_pk_add_f32 / v_pk_mul_f32 (per-component IEEE => bit-exact vs reference);
// contract(off) forbids fma fusion so (dx^2+dy^2)+dz^2 matches jnp exactly.
// Register contract (measured r1-r5): block512 -> arch cap 128, unified 256;
// launch_bounds 2nd arg is IGNORED by this toolchain; block1024 -> cap 64+spill.
#define F1T 512
#define F1PAIR 32

__global__ __launch_bounds__(F1T) void k_fps1(const float* __restrict__ xx,
                                              const float* __restrict__ xy,
                                              const float* __restrict__ xz,
                                              float* __restrict__ ox,
                                              float* __restrict__ oy,
                                              float* __restrict__ oz) {
#pragma clang fp contract(off)
  extern __shared__ v2f zpair[];             // 16384 v2f = 128 KB
  __shared__ float wmax[F1T / 64];
  __shared__ float cc[2][3];                 // double-buffered centroid coords
  __shared__ int S[2];                       // double-buffered winner index
  int tid = threadIdx.x, lane = tid & 63, wv = tid >> 6;   // 8 waves
  v2f px[F1PAIR], py[F1PAIR], d[F1PAIR];
#pragma unroll
  for (int s = 0; s < F1PAIR; ++s) {
    int i0 = (2 * s) * F1T + tid;            // point-major: coalesced global
    int i1 = (2 * s + 1) * F1T + tid;
    px[s] = (v2f){xx[i0], xx[i1]};
    py[s] = (v2f){xy[i0], xy[i1]};
    zpair[s * F1T + tid] = (v2f){xz[i0], xz[i1]};
    d[s] = (v2f){1e10f, 1e10f};
  }
  if (tid == 0) {
    S[0] = 0x7fffffff; S[1] = 0x7fffffff;
    cc[0][0] = xx[0]; cc[0][1] = xy[0]; cc[0][2] = xz[0];   // first centroid = point 0
  }
  __syncthreads();
  for (int it = 0; it < NP1; ++it) {
    float cx = cc[it & 1][0], cy = cc[it & 1][1], cz = cc[it & 1][2];
    if (tid == 0) { ox[it] = cx; oy[it] = cy; oz[it] = cz; }
    v2f cxx = (v2f){cx, cx}, cyy = (v2f){cy, cy}, czz = (v2f){cz, cz};
    float bestv = -1.0f;
#pragma unroll
    for (int s = 0; s < F1PAIR; ++s) {
      v2f zz = zpair[s * F1T + tid];         // ds_read_b64
      v2f dx = px[s] - cxx;                  // v_pk_add_f32 (neg) - exact
      v2f dy = py[s] - cyy;
      v2f dz = zz - czz;
      v2f d2 = ((dx * dx) + (dy * dy)) + (dz * dz);   // pk_mul/pk_add, no fma
      v2f dn;
      dn.x = fminf(d[s].x, d2.x);
      dn.y = fminf(d[s].y, d2.y);
      d[s] = dn;
      bestv = fmaxf(bestv, fmaxf(dn.x, dn.y));
    }
    float wm = bestv;
#pragma unroll
    for (int m = 1; m < 64; m <<= 1) wm = fmaxf(wm, __shfl_xor(wm, m, 64));
    if (lane == 0) wmax[wv] = wm;
    __syncthreads();                         // (A) wmax ready; cc/S reads done
    float gb = wmax[0];
#pragma unroll
    for (int k = 1; k < F1T / 64; ++k) gb = fmaxf(gb, wmax[k]);
    int n = (it + 1) & 1;
    int cand = 0x7fffffff;
    float ccx = 0.f, ccy = 0.f, ccz = 0.f;
    if (bestv == gb) {                       // only waves holding a global max pay this
#pragma unroll
      for (int s = 0; s < F1PAIR; ++s) {
        v2f zz = zpair[s * F1T + tid];
        bool m0 = (d[s].x == gb) && (cand == 0x7fffffff);
        cand = m0 ? ((2 * s) * F1T + tid) : cand;
        ccx = m0 ? px[s].x : ccx;  ccy = m0 ? py[s].x : ccy;  ccz = m0 ? zz.x : ccz;
        bool m1 = (d[s].y == gb) && (cand == 0x7fffffff);
        cand = m1 ? ((2 * s + 1) * F1T + tid) : cand;
        ccx = m1 ? px[s].y : ccx;  ccy = m1 ? py[s].y : ccy;  ccz = m1 ? zz.y : ccz;
      }
      atomicMin(&S[n], cand);                // smallest point index among bit-equal maxima
    }
    __syncthreads();                         // (B) winner final
    if (cand != 0x7fffffff && cand == S[n]) {
      cc[n][0] = ccx; cc[n][1] = ccy; cc[n][2] = ccz;
    }
    if (tid == 0) S[it & 1] = 0x7fffffff;    // reset: becomes atomicMin dst at it+1
    __syncthreads();                         // (C) cc/S ready for next iter
  }
}

// ---------------- FPS2: 512 of 2048, single block, 512 threads x 4 pts ----------------
#define F2T 512
#define F2P 4
__global__ __launch_bounds__(F2T) void k_fps2(const float* __restrict__ x1x,
                                              const float* __restrict__ x1y,
                                              const float* __restrict__ x1z,
                                              float* __restrict__ ox,
                                              float* __restrict__ oy,
                                              float* __restrict__ oz) {
  __shared__ float sx[NP1], sy[NP1], sz[NP1];
  __shared__ float wmax[F2T / 64];
  __shared__ int S[2];
  int tid = threadIdx.x;
  float px[F2P], py[F2P], pz[F2P], d[F2P];
#pragma unroll
  for (int s = 0; s < F2P; ++s) {
    int i = s * F2T + tid;
    px[s] = x1x[i]; py[s] = x1y[i]; pz[s] = x1z[i];
    sx[i] = px[s];  sy[i] = py[s];  sz[i] = pz[s];
    d[s] = 1e10f;
  }
  if (tid == 0) { S[0] = 0; S[1] = 0x7fffffff; }
  __syncthreads();
  for (int it = 0; it < NP2; ++it) {
    int f = __builtin_amdgcn_readfirstlane(S[it & 1]);
    float cx = sx[f], cy = sy[f], cz = sz[f];
    if (tid == 0) { ox[it] = cx; oy[it] = cy; oz[it] = cz; }
    float bestv = -1.0f;
#pragma unroll
    for (int s = 0; s < F2P; ++s) {
      float dx = __fsub_rn(px[s], cx);
      float dy = __fsub_rn(py[s], cy);
      float dz = __fsub_rn(pz[s], cz);
      float d2 = __fadd_rn(__fadd_rn(__fmul_rn(dx, dx), __fmul_rn(dy, dy)), __fmul_rn(dz, dz));
      float dn = fminf(d[s], d2);
      d[s] = dn;
      bestv = fmaxf(bestv, dn);
    }
    float wv = bestv;
#pragma unroll
    for (int m = 1; m < 64; m <<= 1) wv = fmaxf(wv, __shfl_xor(wv, m, 64));
    if ((tid & 63) == 0) wmax[tid >> 6] = wv;
    __syncthreads();
    float gb = wmax[0];
#pragma unroll
    for (int k = 1; k < F2T / 64; ++k) gb = fmaxf(gb, wmax[k]);
    if (bestv == gb) {
      int cand = 0x7fffffff;
#pragma unroll
      for (int s = F2P - 1; s >= 0; --s) cand = (d[s] == gb) ? (s * F2T + tid) : cand;
      atomicMin(&S[(it + 1) & 1], cand);
    }
    if (tid == 0) S[it & 1] = 0x7fffffff;
    __syncthreads();
  }
}

// ---------------- ball query ----------------
__global__ void k_ballq(const float* __restrict__ px, const float* __restrict__ py,
                        const float* __restrict__ pz, int n,
                        const float* __restrict__ qx, const float* __restrict__ qy,
                        const float* __restrict__ qz, int S,
                        float r2, int ns, int* __restrict__ out) {
  int w = (blockIdx.x * (int)blockDim.x + threadIdx.x) >> 6;
  int lane = threadIdx.x & 63;
  if (w >= S) return;
  float cx = qx[w], cy = qy[w], cz = qz[w];
  int found = 0, first = 0;
  bool havefirst = false;
  for (int base = 0; base < n && found < ns; base += 64) {
    int i = base + lane;
    float dx = __fsub_rn(px[i], cx);
    float dy = __fsub_rn(py[i], cy);
    float dz = __fsub_rn(pz[i], cz);
    float d2 = __fadd_rn(__fadd_rn(__fmul_rn(dx, dx), __fmul_rn(dy, dy)), __fmul_rn(dz, dz));
    bool isin = d2 <= r2;
    ull m = __ballot(isin);
    if (!havefirst && m != 0ull) { first = base + __builtin_ctzll(m); havefirst = true; }
    if (isin) {
      int r = (int)__popcll(m & ((1ull << lane) - 1ull));
      int slot = found + r;
      if (slot < ns) out[w * ns + slot] = i;
    }
    found += (int)__popcll(m);
  }
  for (int s2 = found + lane; s2 < ns; s2 += 64) out[w * ns + s2] = first;
}

// ---------------- gather SA1 input rows (15 ch) ----------------
__global__ __launch_bounds__(256) void k_gather1(const float* __restrict__ pts,
                                                 const float* __restrict__ prop,
                                                 const float* __restrict__ xx,
                                                 const float* __restrict__ xy,
                                                 const float* __restrict__ xz,
                                                 const float* __restrict__ x1x,
                                                 const float* __restrict__ x1y,
                                                 const float* __restrict__ x1z,
                                                 const int* __restrict__ gidx,
                                                 float* __restrict__ X, int rbase) {
  int rl = blockIdx.x * 256 + threadIdx.x;
  if (rl >= 8192) return;
  int r = rbase + rl;
  int s = r >> 5;
  int g = gidx[r];
  float x = prop[0], y = prop[1], wz = prop[3];
  float w2 = wz * 0.5f;
  float oxp = __fadd_rn(x, w2), oxm = __fsub_rn(x, w2);
  float oyp = __fadd_rn(y, w2), oym = __fsub_rn(y, w2);
  float gx = xx[g], gy = xy[g], gz = xz[g];
  float pxv = pts[3 * g + 0], pyv = pts[3 * g + 1];
  float* o = X + (size_t)rl * 15;
  o[0] = __fsub_rn(gx, x1x[s]);
  o[1] = __fsub_rn(gy, x1y[s]);
  o[2] = __fsub_rn(gz, x1z[s]);
  o[3] = __fsub_rn(pxv, oxp);  o[4]  = gy;                    o[5]  = gz;
  o[6] = __fsub_rn(pxv, oxm);  o[7]  = gy;                    o[8]  = gz;
  o[9] = gx;                   o[10] = __fsub_rn(pyv, oyp);   o[11] = gz;
  o[12] = gx;                  o[13] = __fsub_rn(pyv, oym);   o[14] = gz;
}

// ---------------- gather SA2 input rows (131 ch) ----------------
__global__ __launch_bounds__(256) void k_gather2(const float* __restrict__ x1x,
                                                 const float* __restrict__ x1y,
                                                 const float* __restrict__ x1z,
                                                 const float* __restrict__ x2x,
                                                 const float* __restrict__ x2y,
                                                 const float* __restrict__ x2z,
                                                 const int* __restrict__ gidx,
                                                 const float* __restrict__ f1,
                                                 float* __restrict__ X, int rbase) {
  int e = blockIdx.x * 256 + threadIdx.x;
  if (e >= 8192 * 131) return;
  int rl = e / 131, c = e % 131;
  int r = rbase + rl;
  int s = r >> 6;
  int g = gidx[r];
  float v;
  if (c == 0)      v = __fsub_rn(x1x[g], x2x[s]);
  else if (c == 1) v = __fsub_rn(x1y[g], x2y[s]);
  else if (c == 2) v = __fsub_rn(x1z[g], x2z[s]);
  else             v = f1[(size_t)g * 128 + (c - 3)];
  X[e] = v;
}

// ---------------- gather SA3 input rows (259 ch) ----------------
__global__ __launch_bounds__(256) void k_gather3(const float* __restrict__ x2x,
                                                 const float* __restrict__ x2y,
                                                 const float* __restrict__ x2z,
                                                 const float* __restrict__ f2,
                                                 float* __restrict__ X) {
  int e = blockIdx.x * 256 + threadIdx.x;
  if (e >= 512 * 259) return;
  int rl = e / 259, c = e % 259;
  float v;
  if (c == 0)      v = x2x[rl];
  else if (c == 1) v = x2y[rl];
  else if (c == 2) v = x2z[rl];
  else             v = f2[(size_t)rl * 256 + (c - 3)];
  X[e] = v;
}

// ---------------- relu GEMM ----------------
__global__ __launch_bounds__(256) void k_gemm(const float* __restrict__ A,
                                              const float* __restrict__ W,
                                              const float* __restrict__ bias,
                                              float* __restrict__ C,
                                              int M, int N, int K) {
  __shared__ __align__(16) float As[16][68];
  __shared__ __align__(16) float Bs[16][68];
  int tid = threadIdx.x;
  int bn = blockIdx.x * 64, bm = blockIdx.y * 64;
  int tx = tid & 15, ty = tid >> 4;
  float acc[4][4] = {{0.f, 0.f, 0.f, 0.f}, {0.f, 0.f, 0.f, 0.f},
                     {0.f, 0.f, 0.f, 0.f}, {0.f, 0.f, 0.f, 0.f}};
  for (int k0 = 0; k0 < K; k0 += 16) {
#pragma unroll
    for (int e = 0; e < 4; ++e) {
      int flat = tid + e * 256;
      int rr = flat >> 4, cc = flat & 15;
      As[cc][rr] = (k0 + cc < K) ? A[(size_t)(bm + rr) * K + (k0 + cc)] : 0.0f;
      Bs[cc][rr] = (k0 + cc < K) ? W[(size_t)(bn + rr) * K + (k0 + cc)] : 0.0f;
    }
    __syncthreads();
#pragma unroll
    for (int kk = 0; kk < 16; ++kk) {
      const float4 a = *(const float4*)&As[kk][ty * 4];
      const float4 b = *(const float4*)&Bs[kk][tx * 4];
      float av[4] = {a.x, a.y, a.z, a.w};
      float bb[4] = {b.x, b.y, b.z, b.w};
#pragma unroll
      for (int i = 0; i < 4; ++i)
#pragma unroll
        for (int j = 0; j < 4; ++j)
          acc[i][j] = fmaf(av[i], bb[j], acc[i][j]);
    }
    __syncthreads();
  }
#pragma unroll
  for (int i = 0; i < 4; ++i) {
    int m = bm + ty * 4 + i;
    float4 o;
    o.x = fmaxf(acc[i][0] + bias[bn + tx * 4 + 0], 0.0f);
    o.y = fmaxf(acc[i][1] + bias[bn + tx * 4 + 1], 0.0f);
    o.z = fmaxf(acc[i][2] + bias[bn + tx * 4 + 2], 0.0f);
    o.w = fmaxf(acc[i][3] + bias[bn + tx * 4 + 3], 0.0f);
    *(float4*)&C[(size_t)m * N + bn + tx * 4] = o;
  }
}

// ---------------- maxpool ----------------
__global__ __launch_bounds__(256) void k_maxpool(const float* __restrict__ H,
                                                 float* __restrict__ F,
                                                 int S, int Ks, int Nch, int sbase) {
  int t = blockIdx.x * 256 + threadIdx.x;
  if (t >= S * Nch) return;
  int sl = t / Nch, n = t % Nch;
  const float* p = H + (size_t)sl * Ks * Nch + n;
  float m = p[0];
  for (int k = 1; k < Ks; ++k) m = fmaxf(m, p[(size_t)k * Nch]);
  F[(size_t)(sbase + sl) * Nch + n] = m;
}

// ---------------- host ----------------
extern "C" void kernel_launch(void* const* d_in, const int* in_sizes, int n_in,
                              void* d_out, int out_size, void* d_ws, size_t ws_size,
                              hipStream_t stream) {
  (void)n_in; (void)out_size; (void)ws_size;
  const float* pts = (const float*)d_in[0];
  const float* prop = (const float*)d_in[1];

  bool dict_order = (in_sizes[3] == 64);
  const float *w[3][3], *b[3][3];
  for (int g = 0; g < 3; ++g)
    for (int l = 0; l < 3; ++l) {
      int base = 2 + g * 6;
      int wi = dict_order ? (base + l * 2) : (base + l);
      int bi = dict_order ? (base + l * 2 + 1) : (base + 3 + l);
      w[g][l] = (const float*)d_in[wi];
      b[g][l] = (const float*)d_in[bi];
    }

  float* ws = (float*)d_ws;
  float* xx = ws;
  float* xy = xx + N_PTS;
  float* xz = xy + N_PTS;
  float* x1x = xz + N_PTS;
  float* x1y = x1x + NP1;
  float* x1z = x1y + NP1;
  float* x2x = x1z + NP1;
  float* x2y = x2x + NP2;
  float* x2z = x2y + NP2;
  int* gidx1 = (int*)(x2z + NP2);
  int* gidx2 = gidx1 + NP1 * NSAMP1;
  float* f1 = (float*)(gidx2 + NP2 * NSAMP2);
  float* f2 = f1 + NP1 * 128;
  float* Xp = f2 + NP2 * 256;
  float* Ha = Xp + 8192 * 131;
  float* Hb = Ha + 8192 * 128;
  float* Hc = Hb + 8192 * 128;

  const float R2A = (float)(0.4 * 0.4);
  const float R2B = (float)(0.8 * 0.8);
  const int F1LDS = N_PTS * (int)sizeof(float);   // 128 KB dynamic LDS (z pairs)

  hipFuncSetAttribute((const void*)k_fps1,
                      hipFuncAttributeMaxDynamicSharedMemorySize, F1LDS);

  k_prep<<<128, 256, 0, stream>>>(pts, prop, xx, xy, xz);
  k_fps1<<<1, F1T, F1LDS, stream>>>(xx, xy, xz, x1x, x1y, x1z);
  k_fps2<<<1, F2T, 0, stream>>>(x1x, x1y, x1z, x2x, x2y, x2z);
  k_ballq<<<512, 256, 0, stream>>>(xx, xy, xz, N_PTS, x1x, x1y, x1z, NP1, R2A, NSAMP1, gidx1);
  k_ballq<<<128, 256, 0, stream>>>(x1x, x1y, x1z, NP1, x2x, x2y, x2z, NP2, R2B, NSAMP2, gidx2);

  for (int ch = 0; ch < 8; ++ch) {
    int rbase = ch * 8192;
    k_gather1<<<32, 256, 0, stream>>>(pts, prop, xx, xy, xz, x1x, x1y, x1z, gidx1, Xp, rbase);
    k_gemm<<<dim3(1, 128), 256, 0, stream>>>(Xp, w[0][0], b[0][0], Ha, 8192, 64, 15);
    k_gemm<<<dim3(1, 128), 256, 0, stream>>>(Ha, w[0][1], b[0][1], Hb, 8192, 64, 64);
    k_gemm<<<dim3(2, 128), 256, 0, stream>>>(Hb, w[0][2], b[0][2], Hc, 8192, 128, 64);
    k_maxpool<<<128, 256, 0, stream>>>(Hc, f1, 256, 32, 128, ch * 256);
  }

  for (int ch = 0; ch < 4; ++ch) {
    int rbase = ch * 8192;
    k_gather2<<<(8192 * 131 + 255) / 256, 256, 0, stream>>>(x1x, x1y, x1z, x2x, x2y, x2z,
                                                            gidx2, f1, Xp, rbase);
    k_gemm<<<dim3(2, 128), 256, 0, stream>>>(Xp, w[1][0], b[1][0], Ha, 8192, 128, 131);
    k_gemm<<<dim3(2, 128), 256, 0, stream>>>(Ha, w[1][1], b[1][1], Hb, 8192, 128, 128);
    k_gemm<<<dim3(4, 128), 256, 0, stream>>>(Hb, w[1][2], b[1][2], Hc, 8192, 256, 128);
    k_maxpool<<<128, 256, 0, stream>>>(Hc, f2, 128, 64, 256, ch * 128);
  }

  k_gather3<<<(512 * 259 + 255) / 256, 256, 0, stream>>>(x2x, x2y, x2z, f2, Xp);
  k_gemm<<<dim3(4, 8), 256, 0, stream>>>(Xp, w[2][0], b[2][0], Ha, 512, 256, 259);
  k_gemm<<<dim3(8, 8), 256, 0, stream>>>(Ha, w[2][1], b[2][1], Hb, 512, 512, 256);
  k_gemm<<<dim3(16, 8), 256, 0, stream>>>(Hb, w[2][2], b[2][2], Hc, 512, 1024, 512);
  k_maxpool<<<4, 256, 0, stream>>>(Hc, (float*)d_out, 1, 512, 1024, 0);
}

// Round 7
// 10533.809 us; speedup vs baseline: 1.8678x; 1.1611x over previous
//
#include <hip/hip_runtime.h>
#include <cstdint>
#include <cstddef>

typedef unsigned long long ull;

#define N_PTS  32768
#define NP1    2048
#define NSAMP1 32
#define NP2    512
#define NSAMP2 64
#define NCH    512            // FPS1 chunks (64 Morton-sorted pts each)

// ---------------- prep: xyz = points - [x,y,0], SoA ----------------
__global__ __launch_bounds__(256) void k_prep(const float* __restrict__ pts,
                                              const float* __restrict__ prop,
                                              float* __restrict__ xx,
                                              float* __restrict__ xy,
                                              float* __restrict__ xz) {
  int t = blockIdx.x * 256 + threadIdx.x;
  if (t >= N_PTS) return;
  float x = prop[0], y = prop[1];
  xx[t] = __fsub_rn(pts[3 * t + 0], x);
  xy[t] = __fsub_rn(pts[3 * t + 1], y);
  xz[t] = pts[3 * t + 2];
}

// ---------------- Morton binning (32^3 bins, cell 0.25 over [-4,4)) ----------------
__device__ inline unsigned part3(unsigned v) {
  v &= 31u;
  v = (v | (v << 8)) & 0x0100Fu;
  v = (v | (v << 4)) & 0x010C3u;
  v = (v | (v << 2)) & 0x09249u;
  return v;
}

__global__ __launch_bounds__(256) void k_morton(const float* __restrict__ xx,
                                                const float* __restrict__ xy,
                                                const float* __restrict__ xz,
                                                int* __restrict__ mcode,
                                                int* __restrict__ hist) {
  int i = blockIdx.x * 256 + threadIdx.x;
  if (i >= N_PTS) return;
  int bx = min(31, max(0, (int)floorf((xx[i] + 4.0f) * 4.0f)));
  int by = min(31, max(0, (int)floorf((xy[i] + 4.0f) * 4.0f)));
  int bz = min(31, max(0, (int)floorf((xz[i] + 4.0f) * 4.0f)));
  int m = (int)(part3((unsigned)bx) | (part3((unsigned)by) << 1) | (part3((unsigned)bz) << 2));
  mcode[i] = m;
  atomicAdd(&hist[m], 1);
}

// ---------------- exclusive scan of 32768-bin histogram (1 block) ----------------
__global__ __launch_bounds__(1024) void k_scan(const int* __restrict__ hist,
                                               int* __restrict__ off) {
  __shared__ int ps[1024];
  int t = threadIdx.x;
  int base = t * 32;
  int loc[32];
  int s = 0;
#pragma unroll
  for (int i = 0; i < 32; ++i) { loc[i] = s; s += hist[base + i]; }
  ps[t] = s;
  __syncthreads();
  for (int ofs = 1; ofs < 1024; ofs <<= 1) {
    int v = (t >= ofs) ? ps[t - ofs] : 0;
    __syncthreads();
    ps[t] += v;
    __syncthreads();
  }
  int ex = (t > 0) ? ps[t - 1] : 0;
#pragma unroll
  for (int i = 0; i < 32; ++i) off[base + i] = ex + loc[i];
}

// ---------------- scatter points into Morton order ----------------
__global__ __launch_bounds__(256) void k_scatter(const float* __restrict__ xx,
                                                 const float* __restrict__ xy,
                                                 const float* __restrict__ xz,
                                                 const int* __restrict__ mcode,
                                                 int* __restrict__ off,
                                                 float* __restrict__ sx,
                                                 float* __restrict__ sy,
                                                 float* __restrict__ sz) {
  int i = blockIdx.x * 256 + threadIdx.x;
  if (i >= N_PTS) return;
  int pos = atomicAdd(&off[mcode[i]], 1);
  sx[pos] = xx[i];
  sy[pos] = xy[i];
  sz[pos] = xz[i];
}

// ---------------- per-chunk bounding sphere (1 wave per chunk) ----------------
__global__ __launch_bounds__(64) void k_chunkb(const float* __restrict__ sx,
                                               const float* __restrict__ sy,
                                               const float* __restrict__ sz,
                                               float4* __restrict__ cb) {
  int ch = blockIdx.x, lane = threadIdx.x;
  int i = ch * 64 + lane;
  float x = sx[i], y = sy[i], z = sz[i];
  float mnx = x, mxx = x, mny = y, mxy = y, mnz = z, mxz = z;
#pragma unroll
  for (int m = 1; m < 64; m <<= 1) {
    mnx = fminf(mnx, __shfl_xor(mnx, m, 64)); mxx = fmaxf(mxx, __shfl_xor(mxx, m, 64));
    mny = fminf(mny, __shfl_xor(mny, m, 64)); mxy = fmaxf(mxy, __shfl_xor(mxy, m, 64));
    mnz = fminf(mnz, __shfl_xor(mnz, m, 64)); mxz = fmaxf(mxz, __shfl_xor(mxz, m, 64));
  }
  float cx = 0.5f * (mnx + mxx), cy = 0.5f * (mny + mxy), cz = 0.5f * (mnz + mxz);
  float dx = x - cx, dy = y - cy, dz = z - cz;
  float r2 = dx * dx + dy * dy + dz * dz;
#pragma unroll
  for (int m = 1; m < 64; m <<= 1) r2 = fmaxf(r2, __shfl_xor(r2, m, 64));
  if (lane == 0) {
    float r = sqrtf(r2) * 1.00002f + 1e-6f;
    cb[ch] = make_float4(cx, cy, cz, r);
  }
}

// ---------------- FPS1: chunk-pruned, register/LDS-resident, 1 block x 512 ----------
// Wave w owns chunks {c : c%8==w}; slice s <-> chunk s*8+w; lane l <-> point
// (s*8+w)*64+l. px/py/d in regs (192; block512 => no scratch, overflow->AGPR,
// touched only on processed slices). z in LDS; chunk spheres + (dmax,~idx) u64
// keys in LDS. Per iter: wave-uniform ballot of 64 bound tests -> statically
// unrolled guarded slices (skip = 2 scalar insts) -> 512-key u64 argmax ->
// winner coords from L2-hot sorted arrays. d-update chain bit-exact vs ref.
#define F1T 512

__global__ __launch_bounds__(F1T) void k_fps1s(const float* __restrict__ sxx,
                                               const float* __restrict__ sxy,
                                               const float* __restrict__ sxz,
                                               const float4* __restrict__ cbg,
                                               const float* __restrict__ xx,
                                               const float* __restrict__ xy,
                                               const float* __restrict__ xz,
                                               float* __restrict__ ox,
                                               float* __restrict__ oy,
                                               float* __restrict__ oz) {
  extern __shared__ float dyn[];
  float* zs = dyn;                            // 32768 f32 = 128 KB
  float4* cb = (float4*)(dyn + N_PTS);        // 512 float4 = 8 KB
  ull* ckey = (ull*)(cb + NCH);               // 512 u64 = 4 KB
  __shared__ ull wkeys[F1T / 64];
  __shared__ float cc[2][3];
  int tid = threadIdx.x, lane = tid & 63, wv = tid >> 6;   // 8 waves
  float px[64], py[64], d[64];
#pragma unroll
  for (int s = 0; s < 64; ++s) {
    int p = ((s * 8 + wv) << 6) + lane;       // coalesced per slice
    px[s] = sxx[p];
    py[s] = sxy[p];
    zs[p] = sxz[p];
    d[s] = 1e10f;
  }
  if (tid < NCH) {
    cb[tid] = cbg[tid];
    ckey[tid] = ((ull)__float_as_uint(1e10f) << 32);   // forces full processing at it=0
  }
  if (tid == 0) { cc[0][0] = xx[0]; cc[0][1] = xy[0]; cc[0][2] = xz[0]; }
  __syncthreads();
  for (int it = 0; it < NP1; ++it) {
    int cur = it & 1, nxt = cur ^ 1;
    float cx = cc[cur][0], cy = cc[cur][1], cz = cc[cur][2];
    if (tid == 0) { ox[it] = cx; oy[it] = cy; oz[it] = cz; }
    // ---- wave-uniform chunk tests: lane L tests chunk L*8+wv (= bit L) ----
    int tch = lane * 8 + wv;
    float4 bs = cb[tch];
    float chmax = __uint_as_float((unsigned)(ckey[tch] >> 32));
    float tdx = cx - bs.x, tdy = cy - bs.y, tdz = cz - bs.z;
    float sd = sqrtf(tdx * tdx + tdy * tdy + tdz * tdz);
    float md = sd * 0.99999f - bs.w;          // conservative lower bound
    bool proc = !(md > 0.0f && md * md * 0.99999f > chmax * 1.00001f);
    ull mask = __ballot(proc);
    // ---- statically unrolled guarded slices ----
#pragma unroll
    for (int s = 0; s < 64; ++s) {
      if ((mask >> s) & 1ull) {
        int ch = s * 8 + wv;
        int p = (ch << 6) + lane;
        float z = zs[p];
        // exact reference arithmetic: no fma, (dx^2 + dy^2) + dz^2
        float dx = __fsub_rn(px[s], cx);
        float dy = __fsub_rn(py[s], cy);
        float dz = __fsub_rn(z, cz);
        float d2 = __fadd_rn(__fadd_rn(__fmul_rn(dx, dx), __fmul_rn(dy, dy)),
                             __fmul_rn(dz, dz));
        float dn = fminf(d[s], d2);
        d[s] = dn;
        float wm = dn;
#pragma unroll
        for (int m = 1; m < 64; m <<= 1) wm = fmaxf(wm, __shfl_xor(wm, m, 64));
        ull bm = __ballot(dn == wm);
        int wl = __builtin_ctzll(bm);          // smallest sorted idx on in-chunk ties
        if (lane == wl) ckey[ch] = ((ull)__float_as_uint(wm) << 32) | (unsigned)(~p);
      }
    }
    __syncthreads();                           // (A) keys final
    // ---- global argmax over 512 chunk keys ----
    ull k = ckey[tid];
#pragma unroll
    for (int m = 1; m < 64; m <<= 1) { ull o = __shfl_xor(k, m, 64); k = (o > k) ? o : k; }
    if (lane == 0) wkeys[wv] = k;
    __syncthreads();                           // (B) wave partials ready
    if (tid < 64) {
      ull k2 = (lane < F1T / 64) ? wkeys[lane] : 0ull;
#pragma unroll
      for (int m = 1; m < F1T / 64; m <<= 1) { ull o = __shfl_xor(k2, m, 64); k2 = (o > k2) ? o : k2; }
      if (lane == 0) {
        int f = (int)(~(unsigned)k2);          // winning sorted index
        cc[nxt][0] = sxx[f];                   // L2-hot (384 KB resident)
        cc[nxt][1] = sxy[f];
        cc[nxt][2] = zs[f];
      }
    }
    __syncthreads();                           // (C) next centroid ready
  }
}

// ---------------- FPS2: 512 of 2048, single block, 512 threads x 4 pts ----------------
#define F2T 512
#define F2P 4
__global__ __launch_bounds__(F2T) void k_fps2(const float* __restrict__ x1x,
                                              const float* __restrict__ x1y,
                                              const float* __restrict__ x1z,
                                              float* __restrict__ ox,
                                              float* __restrict__ oy,
                                              float* __restrict__ oz) {
  __shared__ float sx[NP1], sy[NP1], sz[NP1];
  __shared__ float wmax[F2T / 64];
  __shared__ int S[2];
  int tid = threadIdx.x;
  float px[F2P], py[F2P], pz[F2P], d[F2P];
#pragma unroll
  for (int s = 0; s < F2P; ++s) {
    int i = s * F2T + tid;
    px[s] = x1x[i]; py[s] = x1y[i]; pz[s] = x1z[i];
    sx[i] = px[s];  sy[i] = py[s];  sz[i] = pz[s];
    d[s] = 1e10f;
  }
  if (tid == 0) { S[0] = 0; S[1] = 0x7fffffff; }
  __syncthreads();
  for (int it = 0; it < NP2; ++it) {
    int f = __builtin_amdgcn_readfirstlane(S[it & 1]);
    float cx = sx[f], cy = sy[f], cz = sz[f];
    if (tid == 0) { ox[it] = cx; oy[it] = cy; oz[it] = cz; }
    float bestv = -1.0f;
#pragma unroll
    for (int s = 0; s < F2P; ++s) {
      float dx = __fsub_rn(px[s], cx);
      float dy = __fsub_rn(py[s], cy);
      float dz = __fsub_rn(pz[s], cz);
      float d2 = __fadd_rn(__fadd_rn(__fmul_rn(dx, dx), __fmul_rn(dy, dy)), __fmul_rn(dz, dz));
      float dn = fminf(d[s], d2);
      d[s] = dn;
      bestv = fmaxf(bestv, dn);
    }
    float wv = bestv;
#pragma unroll
    for (int m = 1; m < 64; m <<= 1) wv = fmaxf(wv, __shfl_xor(wv, m, 64));
    if ((tid & 63) == 0) wmax[tid >> 6] = wv;
    __syncthreads();
    float gb = wmax[0];
#pragma unroll
    for (int k = 1; k < F2T / 64; ++k) gb = fmaxf(gb, wmax[k]);
    if (bestv == gb) {
      int cand = 0x7fffffff;
#pragma unroll
      for (int s = F2P - 1; s >= 0; --s) cand = (d[s] == gb) ? (s * F2T + tid) : cand;
      atomicMin(&S[(it + 1) & 1], cand);
    }
    if (tid == 0) S[it & 1] = 0x7fffffff;
    __syncthreads();
  }
}

// ---------------- ball query ----------------
__global__ void k_ballq(const float* __restrict__ px, const float* __restrict__ py,
                        const float* __restrict__ pz, int n,
                        const float* __restrict__ qx, const float* __restrict__ qy,
                        const float* __restrict__ qz, int S,
                        float r2, int ns, int* __restrict__ out) {
  int w = (blockIdx.x * (int)blockDim.x + threadIdx.x) >> 6;
  int lane = threadIdx.x & 63;
  if (w >= S) return;
  float cx = qx[w], cy = qy[w], cz = qz[w];
  int found = 0, first = 0;
  bool havefirst = false;
  for (int base = 0; base < n && found < ns; base += 64) {
    int i = base + lane;
    float dx = __fsub_rn(px[i], cx);
    float dy = __fsub_rn(py[i], cy);
    float dz = __fsub_rn(pz[i], cz);
    float d2 = __fadd_rn(__fadd_rn(__fmul_rn(dx, dx), __fmul_rn(dy, dy)), __fmul_rn(dz, dz));
    bool isin = d2 <= r2;
    ull m = __ballot(isin);
    if (!havefirst && m != 0ull) { first = base + __builtin_ctzll(m); havefirst = true; }
    if (isin) {
      int r = (int)__popcll(m & ((1ull << lane) - 1ull));
      int slot = found + r;
      if (slot < ns) out[w * ns + slot] = i;
    }
    found += (int)__popcll(m);
  }
  for (int s2 = found + lane; s2 < ns; s2 += 64) out[w * ns + s2] = first;
}

// ---------------- gather SA1 input rows (15 ch) ----------------
__global__ __launch_bounds__(256) void k_gather1(const float* __restrict__ pts,
                                                 const float* __restrict__ prop,
                                                 const float* __restrict__ xx,
                                                 const float* __restrict__ xy,
                                                 const float* __restrict__ xz,
                                                 const float* __restrict__ x1x,
                                                 const float* __restrict__ x1y,
                                                 const float* __restrict__ x1z,
                                                 const int* __restrict__ gidx,
                                                 float* __restrict__ X, int rbase) {
  int rl = blockIdx.x * 256 + threadIdx.x;
  if (rl >= 8192) return;
  int r = rbase + rl;
  int s = r >> 5;
  int g = gidx[r];
  float x = prop[0], y = prop[1], wz = prop[3];
  float w2 = wz * 0.5f;
  float oxp = __fadd_rn(x, w2), oxm = __fsub_rn(x, w2);
  float oyp = __fadd_rn(y, w2), oym = __fsub_rn(y, w2);
  float gx = xx[g], gy = xy[g], gz = xz[g];
  float pxv = pts[3 * g + 0], pyv = pts[3 * g + 1];
  float* o = X + (size_t)rl * 15;
  o[0] = __fsub_rn(gx, x1x[s]);
  o[1] = __fsub_rn(gy, x1y[s]);
  o[2] = __fsub_rn(gz, x1z[s]);
  o[3] = __fsub_rn(pxv, oxp);  o[4]  = gy;                    o[5]  = gz;
  o[6] = __fsub_rn(pxv, oxm);  o[7]  = gy;                    o[8]  = gz;
  o[9] = gx;                   o[10] = __fsub_rn(pyv, oyp);   o[11] = gz;
  o[12] = gx;                  o[13] = __fsub_rn(pyv, oym);   o[14] = gz;
}

// ---------------- gather SA2 input rows (131 ch) ----------------
__global__ __launch_bounds__(256) void k_gather2(const float* __restrict__ x1x,
                                                 const float* __restrict__ x1y,
                                                 const float* __restrict__ x1z,
                                                 const float* __restrict__ x2x,
                                                 const float* __restrict__ x2y,
                                                 const float* __restrict__ x2z,
                                                 const int* __restrict__ gidx,
                                                 const float* __restrict__ f1,
                                                 float* __restrict__ X, int rbase) {
  int e = blockIdx.x * 256 + threadIdx.x;
  if (e >= 8192 * 131) return;
  int rl = e / 131, c = e % 131;
  int r = rbase + rl;
  int s = r >> 6;
  int g = gidx[r];
  float v;
  if (c == 0)      v = __fsub_rn(x1x[g], x2x[s]);
  else if (c == 1) v = __fsub_rn(x1y[g], x2y[s]);
  else if (c == 2) v = __fsub_rn(x1z[g], x2z[s]);
  else             v = f1[(size_t)g * 128 + (c - 3)];
  X[e] = v;
}

// ---------------- gather SA3 input rows (259 ch) ----------------
__global__ __launch_bounds__(256) void k_gather3(const float* __restrict__ x2x,
                                                 const float* __restrict__ x2y,
                                                 const float* __restrict__ x2z,
                                                 const float* __restrict__ f2,
                                                 float* __restrict__ X) {
  int e = blockIdx.x * 256 + threadIdx.x;
  if (e >= 512 * 259) return;
  int rl = e / 259, c = e % 259;
  float v;
  if (c == 0)      v = x2x[rl];
  else if (c == 1) v = x2y[rl];
  else if (c == 2) v = x2z[rl];
  else             v = f2[(size_t)rl * 256 + (c - 3)];
  X[e] = v;
}

// ---------------- relu GEMM ----------------
__global__ __launch_bounds__(256) void k_gemm(const float* __restrict__ A,
                                              const float* __restrict__ W,
                                              const float* __restrict__ bias,
                                              float* __restrict__ C,
                                              int M, int N, int K) {
  __shared__ __align__(16) float As[16][68];
  __shared__ __align__(16) float Bs[16][68];
  int tid = threadIdx.x;
  int bn = blockIdx.x * 64, bm = blockIdx.y * 64;
  int tx = tid & 15, ty = tid >> 4;
  float acc[4][4] = {{0.f, 0.f, 0.f, 0.f}, {0.f, 0.f, 0.f, 0.f},
                     {0.f, 0.f, 0.f, 0.f}, {0.f, 0.f, 0.f, 0.f}};
  for (int k0 = 0; k0 < K; k0 += 16) {
#pragma unroll
    for (int e = 0; e < 4; ++e) {
      int flat = tid + e * 256;
      int rr = flat >> 4, cc = flat & 15;
      As[cc][rr] = (k0 + cc < K) ? A[(size_t)(bm + rr) * K + (k0 + cc)] : 0.0f;
      Bs[cc][rr] = (k0 + cc < K) ? W[(size_t)(bn + rr) * K + (k0 + cc)] : 0.0f;
    }
    __syncthreads();
#pragma unroll
    for (int kk = 0; kk < 16; ++kk) {
      const float4 a = *(const float4*)&As[kk][ty * 4];
      const float4 b = *(const float4*)&Bs[kk][tx * 4];
      float av[4] = {a.x, a.y, a.z, a.w};
      float bb[4] = {b.x, b.y, b.z, b.w};
#pragma unroll
      for (int i = 0; i < 4; ++i)
#pragma unroll
        for (int j = 0; j < 4; ++j)
          acc[i][j] = fmaf(av[i], bb[j], acc[i][j]);
    }
    __syncthreads();
  }
#pragma unroll
  for (int i = 0; i < 4; ++i) {
    int m = bm + ty * 4 + i;
    float4 o;
    o.x = fmaxf(acc[i][0] + bias[bn + tx * 4 + 0], 0.0f);
    o.y = fmaxf(acc[i][1] + bias[bn + tx * 4 + 1], 0.0f);
    o.z = fmaxf(acc[i][2] + bias[bn + tx * 4 + 2], 0.0f);
    o.w = fmaxf(acc[i][3] + bias[bn + tx * 4 + 3], 0.0f);
    *(float4*)&C[(size_t)m * N + bn + tx * 4] = o;
  }
}

// ---------------- maxpool ----------------
__global__ __launch_bounds__(256) void k_maxpool(const float* __restrict__ H,
                                                 float* __restrict__ F,
                                                 int S, int Ks, int Nch, int sbase) {
  int t = blockIdx.x * 256 + threadIdx.x;
  if (t >= S * Nch) return;
  int sl = t / Nch, n = t % Nch;
  const float* p = H + (size_t)sl * Ks * Nch + n;
  float m = p[0];
  for (int k = 1; k < Ks; ++k) m = fmaxf(m, p[(size_t)k * Nch]);
  F[(size_t)(sbase + sl) * Nch + n] = m;
}

// ---------------- host ----------------
extern "C" void kernel_launch(void* const* d_in, const int* in_sizes, int n_in,
                              void* d_out, int out_size, void* d_ws, size_t ws_size,
                              hipStream_t stream) {
  (void)n_in; (void)out_size; (void)ws_size;
  const float* pts = (const float*)d_in[0];
  const float* prop = (const float*)d_in[1];

  bool dict_order = (in_sizes[3] == 64);
  const float *w[3][3], *b[3][3];
  for (int g = 0; g < 3; ++g)
    for (int l = 0; l < 3; ++l) {
      int base = 2 + g * 6;
      int wi = dict_order ? (base + l * 2) : (base + l);
      int bi = dict_order ? (base + l * 2 + 1) : (base + 3 + l);
      w[g][l] = (const float*)d_in[wi];
      b[g][l] = (const float*)d_in[bi];
    }

  float* ws = (float*)d_ws;
  float* xx = ws;
  float* xy = xx + N_PTS;
  float* xz = xy + N_PTS;
  float* x1x = xz + N_PTS;
  float* x1y = x1x + NP1;
  float* x1z = x1y + NP1;
  float* x2x = x1z + NP1;
  float* x2y = x2x + NP2;
  float* x2z = x2y + NP2;
  int* gidx1 = (int*)(x2z + NP2);
  int* gidx2 = gidx1 + NP1 * NSAMP1;
  float* f1 = (float*)(gidx2 + NP2 * NSAMP2);
  float* f2 = f1 + NP1 * 128;
  float* Xp = f2 + NP2 * 256;                // 8192*131 pool
  float* Ha = Xp + 8192 * 131;
  float* Hb = Ha + 8192 * 128;
  float* Hc = Hb + 8192 * 128;

  // FPS1 sort scratch aliased into Xp (unused until gather1)
  int*   mcode = (int*)Xp;                   // 32768
  int*   hist  = mcode + N_PTS;              // 32768
  float* sxx   = (float*)(hist + N_PTS);     // 32768
  float* sxy   = sxx + N_PTS;
  float* sxz   = sxy + N_PTS;
  float4* cbv  = (float4*)(sxz + N_PTS);     // 512 float4 (16B-aligned)

  const float R2A = (float)(0.4 * 0.4);
  const float R2B = (float)(0.8 * 0.8);
  const int F1LDS = N_PTS * (int)sizeof(float) + NCH * 16 + NCH * 8;   // 143360 B

  hipFuncSetAttribute((const void*)k_fps1s,
                      hipFuncAttributeMaxDynamicSharedMemorySize, F1LDS);

  k_prep<<<128, 256, 0, stream>>>(pts, prop, xx, xy, xz);
  hipMemsetAsync(hist, 0, N_PTS * sizeof(int), stream);
  k_morton<<<128, 256, 0, stream>>>(xx, xy, xz, mcode, hist);
  k_scan<<<1, 1024, 0, stream>>>(hist, hist);
  k_scatter<<<128, 256, 0, stream>>>(xx, xy, xz, mcode, hist, sxx, sxy, sxz);
  k_chunkb<<<NCH, 64, 0, stream>>>(sxx, sxy, sxz, cbv);
  k_fps1s<<<1, F1T, F1LDS, stream>>>(sxx, sxy, sxz, cbv, xx, xy, xz, x1x, x1y, x1z);
  k_fps2<<<1, F2T, 0, stream>>>(x1x, x1y, x1z, x2x, x2y, x2z);
  k_ballq<<<512, 256, 0, stream>>>(xx, xy, xz, N_PTS, x1x, x1y, x1z, NP1, R2A, NSAMP1, gidx1);
  k_ballq<<<128, 256, 0, stream>>>(x1x, x1y, x1z, NP1, x2x, x2y, x2z, NP2, R2B, NSAMP2, gidx2);

  for (int ch = 0; ch < 8; ++ch) {
    int rbase = ch * 8192;
    k_gather1<<<32, 256, 0, stream>>>(pts, prop, xx, xy, xz, x1x, x1y, x1z, gidx1, Xp, rbase);
    k_gemm<<<dim3(1, 128), 256, 0, stream>>>(Xp, w[0][0], b[0][0], Ha, 8192, 64, 15);
    k_gemm<<<dim3(1, 128), 256, 0, stream>>>(Ha, w[0][1], b[0][1], Hb, 8192, 64, 64);
    k_gemm<<<dim3(2, 128), 256, 0, stream>>>(Hb, w[0][2], b[0][2], Hc, 8192, 128, 64);
    k_maxpool<<<128, 256, 0, stream>>>(Hc, f1, 256, 32, 128, ch * 256);
  }

  for (int ch = 0; ch < 4; ++ch) {
    int rbase = ch * 8192;
    k_gather2<<<(8192 * 131 + 255) / 256, 256, 0, stream>>>(x1x, x1y, x1z, x2x, x2y, x2z,
                                                            gidx2, f1, Xp, rbase);
    k_gemm<<<dim3(2, 128), 256, 0, stream>>>(Xp, w[1][0], b[1][0], Ha, 8192, 128, 131);
    k_gemm<<<dim3(2, 128), 256, 0, stream>>>(Ha, w[1][1], b[1][1], Hb, 8192, 128, 128);
    k_gemm<<<dim3(4, 128), 256, 0, stream>>>(Hb, w[1][2], b[1][2], Hc, 8192, 256, 128);
    k_maxpool<<<128, 256, 0, stream>>>(Hc, f2, 128, 64, 256, ch * 128);
  }

  k_gather3<<<(512 * 259 + 255) / 256, 256, 0, stream>>>(x2x, x2y, x2z, f2, Xp);
  k_gemm<<<dim3(4, 8), 256, 0, stream>>>(Xp, w[2][0], b[2][0], Ha, 512, 256, 259);
  k_gemm<<<dim3(8, 8), 256, 0, stream>>>(Ha, w[2][1], b[2][1], Hb, 512, 512, 256);
  k_gemm<<<dim3(16, 8), 256, 0, stream>>>(Hb, w[2][2], b[2][2], Hc, 512, 1024, 512);
  k_maxpool<<<4, 256, 0, stream>>>(Hc, (float*)d_out, 1, 512, 1024, 0);
}